// Round 3
// baseline (518.693 us; speedup 1.0000x reference)
//
#include <hip/hip_runtime.h>
#include <hip/hip_bf16.h>

#define N_NODES 10000
#define N_EDGES 160000
#define DD 1024
#define KCAT 2048
#define MPAD 10240
#define MTILES 79   // ceil(10000/128), covers rows 0..10111
#define NTILES 8
#define NBLK (MTILES * NTILES)   // 632 = 8*79

// agg grid: 8 column-slices (one per XCD via blockIdx%8) x 125 blocks
#define AGG_BLOCKS 1000
#define AGG_WPS 500   // waves per slice = (AGG_BLOCKS/8)*4

typedef __attribute__((ext_vector_type(8))) __bf16 bf16x8;
typedef __attribute__((ext_vector_type(4))) __bf16 bf16x4;
typedef __attribute__((ext_vector_type(4))) float f32x4;

// ---------------- async global->LDS (16B, linear dest) ----------------
__device__ inline void gload_lds16(const void* g, void* l) {
  __builtin_amdgcn_global_load_lds((const __attribute__((address_space(1))) void*)g,
                                   (__attribute__((address_space(3))) void*)l, 16, 0, 0);
}

// ---------------- CSR build ----------------
__global__ __launch_bounds__(256) void k_hist(const int* __restrict__ dst,
                                              int* __restrict__ deg) {
  int e = blockIdx.x * 256 + threadIdx.x;
  if (e < N_EDGES) atomicAdd(&deg[dst[e]], 1);
}

// 1024 threads, 10 elems/thread, shfl wave-scan + serial wave-total scan (3 barriers)
__global__ __launch_bounds__(1024) void k_scan(const int* __restrict__ deg,
                                               int* __restrict__ off) {
  int t = threadIdx.x;
  int base_i = t * 10;
  int loc[10];
  int sum = 0;
#pragma unroll
  for (int j = 0; j < 10; ++j) {
    int idx = base_i + j;
    int v = (idx < N_NODES) ? deg[idx] : 0;
    loc[j] = sum;           // exclusive within chunk
    sum += v;
  }
  int lane = t & 63, w = t >> 6;
  int inc = sum;            // inclusive wave scan of chunk totals
#pragma unroll
  for (int d = 1; d < 64; d <<= 1) {
    int y = __shfl_up(inc, d);
    if (lane >= d) inc += y;
  }
  __shared__ int wtot[16];
  __shared__ int wpre[16];
  if (lane == 63) wtot[w] = inc;
  __syncthreads();
  if (t == 0) {
    int c = 0;
    for (int k = 0; k < 16; ++k) { wpre[k] = c; c += wtot[k]; }
    off[N_NODES] = c;       // total edges
  }
  __syncthreads();
  int tbase = wpre[w] + (inc - sum);   // exclusive prefix at this thread's chunk start
#pragma unroll
  for (int j = 0; j < 10; ++j) {
    int idx = base_i + j;
    if (idx < N_NODES) off[idx] = tbase + loc[j];
  }
}

__global__ __launch_bounds__(256) void k_fill(const int* __restrict__ src,
                                              const int* __restrict__ dst,
                                              const int* __restrict__ off,
                                              int* __restrict__ cursor,
                                              int* __restrict__ eidx) {
  int e = blockIdx.x * 256 + threadIdx.x;
  if (e < N_EDGES) {
    int d = dst[e];
    int pos = atomicAdd(&cursor[d], 1);
    eidx[off[d] + pos] = src[e];
  }
}

// ---------------- embedding gather -> bf16 (left half of xcat) ----------------
__global__ __launch_bounds__(256) void k_embed(const int* __restrict__ node,
                                               const float* __restrict__ emb,
                                               __bf16* __restrict__ xcat) {
  int i = blockIdx.x;
  int t = threadIdx.x;
  float4 v = ((const float4*)(emb + (size_t)node[i] * DD))[t];
  bf16x4 o;
  o[0] = (__bf16)v.x; o[1] = (__bf16)v.y; o[2] = (__bf16)v.z; o[3] = (__bf16)v.w;
  *(bf16x4*)(xcat + (size_t)i * KCAT + t * 4) = o;
}

// ---------------- weights: [Wself;Wneigh] -> W^T bf16 [1024][2048] ----------------
__global__ __launch_bounds__(256) void k_wconv(const float* __restrict__ Ws,
                                               const float* __restrict__ Wn,
                                               __bf16* __restrict__ Wt) {
  __shared__ float tile[32][33];
  int k0 = blockIdx.x * 32;
  int c0 = blockIdx.y * 32;
  for (int i = threadIdx.y; i < 32; i += 8) {
    int k = k0 + i, c = c0 + threadIdx.x;
    float v = (k < DD) ? Ws[(size_t)k * DD + c] : Wn[(size_t)(k - DD) * DD + c];
    tile[i][threadIdx.x] = v;
  }
  __syncthreads();
  for (int i = threadIdx.y; i < 32; i += 8) {
    int c = c0 + i, k = k0 + threadIdx.x;
    Wt[(size_t)c * KCAT + k] = (__bf16)tile[threadIdx.x][i];
  }
}

// ---------------- mean aggregation: column-sliced, XCD-pinned ----------------
// Slice s = blockIdx%8 -> XCD s (HW round-robin). Each slice covers cols
// [128s, 128s+128) of the left half for ALL nodes: per-XCD read set = 2.56 MB
// -> L2-resident; edge reuse (~16x) served from private L2 instead of L3.
// Per lane: 1 dword (2 bf16) per edge row; wave reads 256B contiguous.
__global__ __launch_bounds__(256) void k_agg(__bf16* __restrict__ buf,
                                             const int* __restrict__ off,
                                             const int* __restrict__ eidx) {
  const int s    = blockIdx.x & 7;            // column slice / XCD
  const int q    = blockIdx.x >> 3;           // 0..124
  const int lane = threadIdx.x & 63;
  const int w    = threadIdx.x >> 6;
  const int wid  = q * 4 + w;                 // 0..499 wave id within slice
  const size_t colb = (size_t)s * 128 + lane * 2;   // bf16 col of this lane's pair

  for (int n = wid; n < N_NODES; n += AGG_WPS) {
    int s0 = off[n], e0 = off[n + 1];
    float a0 = 0.f, a1 = 0.f, b0 = 0.f, b1 = 0.f;
    int i = s0;
    for (; i + 2 <= e0; i += 2) {
      const __bf16* r0 = buf + (size_t)eidx[i] * KCAT + colb;
      const __bf16* r1 = buf + (size_t)eidx[i + 1] * KCAT + colb;
      a0 += (float)r0[0]; a1 += (float)r0[1];
      b0 += (float)r1[0]; b1 += (float)r1[1];
    }
    if (i < e0) {
      const __bf16* r0 = buf + (size_t)eidx[i] * KCAT + colb;
      a0 += (float)r0[0]; a1 += (float)r0[1];
    }
    float inv = 1.0f / fmaxf((float)(e0 - s0), 1.0f);
    __bf16 o0 = (__bf16)((a0 + b0) * inv);
    __bf16 o1 = (__bf16)((a1 + b1) * inv);
    __bf16* dstp = buf + (size_t)n * KCAT + DD + colb;
    dstp[0] = o0; dstp[1] = o1;
  }
}

// ---------------- GEMM: C[M,1024] = A[M,2048] @ Wt^T + bias ----------------
// 128x128 tile, BK=64, 4 waves (2x2), T3-minimum 2-phase double-buffered LDS.
// LDS 64KB (2 x (16KB A | 16KB B)). Pre-swizzled global source + XOR-swizzled
// ds_read (byte ^= (row&7)<<4), linear gload_lds dest (rule #21).
// Block decode: bijective XCD-chunked, N-fastest (632 = 8*79) for A-panel L2 reuse.
template <int MODE>
__global__ __launch_bounds__(256, 2) void k_gemm(const __bf16* __restrict__ A,
                                                 const __bf16* __restrict__ Bt,
                                                 const float* __restrict__ bias,
                                                 float* __restrict__ Cf,
                                                 __bf16* __restrict__ Cb,
                                                 int Mreal) {
  __shared__ char smem[65536];
  const int tid  = threadIdx.x;
  const int lane = tid & 63;
  const int w    = tid >> 6;
  const int wr   = w >> 1, wc = w & 1;
  const int b  = blockIdx.x;
  const int l  = (b & 7) * MTILES + (b >> 3);
  const int m0 = (l >> 3) * 128;
  const int n0 = (l & 7) * 128;

  f32x4 acc[4][4];
#pragma unroll
  for (int m = 0; m < 4; ++m)
#pragma unroll
    for (int n = 0; n < 4; ++n) acc[m][n] = f32x4{0.f, 0.f, 0.f, 0.f};

  // staging source coords: granule G = chunk*64+lane, E = G ^ ((G>>3)&7)
  int sr[4], sk[4];
#pragma unroll
  for (int i = 0; i < 4; ++i) {
    int G = (4 * w + i) * 64 + lane;
    int E = G ^ ((G >> 3) & 7);
    sr[i] = E >> 3;
    sk[i] = (E & 7) * 8;
  }

  auto stage = [&](int buf, int kt) {
    char* As = smem + buf * 32768;
    char* Bs = As + 16384;
#pragma unroll
    for (int i = 0; i < 4; ++i) {
      gload_lds16(A + (size_t)(m0 + sr[i]) * KCAT + (kt + sk[i]), As + (4 * w + i) * 1024);
      gload_lds16(Bt + (size_t)(n0 + sr[i]) * KCAT + (kt + sk[i]), Bs + (4 * w + i) * 1024);
    }
  };

  auto compute = [&](int buf) {
    char* As = smem + buf * 32768;
    char* Bs = As + 16384;
#pragma unroll
    for (int kk = 0; kk < 64; kk += 32) {
      const int koff = kk + ((lane >> 4) * 8);
      bf16x8 af[4], bfr[4];
#pragma unroll
      for (int m = 0; m < 4; ++m) {
        int r = wr * 64 + m * 16 + (lane & 15);
        int byte = ((r * 64 + koff) * 2) ^ ((r & 7) << 4);
        af[m] = *(const bf16x8*)(As + byte);
      }
#pragma unroll
      for (int n = 0; n < 4; ++n) {
        int c = wc * 64 + n * 16 + (lane & 15);
        int byte = ((c * 64 + koff) * 2) ^ ((c & 7) << 4);
        bfr[n] = *(const bf16x8*)(Bs + byte);
      }
#pragma unroll
      for (int m = 0; m < 4; ++m)
#pragma unroll
        for (int n = 0; n < 4; ++n)
          acc[m][n] = __builtin_amdgcn_mfma_f32_16x16x32_bf16(af[m], bfr[n], acc[m][n], 0, 0, 0);
    }
  };

  // T3-minimum 2-phase pipeline
  stage(0, 0);
  __syncthreads();
  int cur = 0;
  for (int kt = 0; kt < KCAT; kt += 64) {
    if (kt + 64 < KCAT) stage(cur ^ 1, kt + 64);  // issue next-tile loads first
    compute(cur);                                  // ds_read + MFMA on current
    __syncthreads();                               // single drain per K-step
    cur ^= 1;
  }

  // epilogue: C/D layout col=lane&15, row=(lane>>4)*4+j (m89-verified)
  const int rb = m0 + wr * 64;
  const int cb = n0 + wc * 64;
#pragma unroll
  for (int m = 0; m < 4; ++m) {
#pragma unroll
    for (int n = 0; n < 4; ++n) {
      int c = cb + n * 16 + (lane & 15);
      float bv = bias[c];
#pragma unroll
      for (int j = 0; j < 4; ++j) {
        int r = rb + m * 16 + (lane >> 4) * 4 + j;
        if (r < Mreal) {
          float v = acc[m][n][j] + bv;
          if constexpr (MODE == 1) {
            v = fmaxf(v, 0.f);
            Cb[(size_t)r * KCAT + c] = (__bf16)v;   // left half of hcat
          } else {
            Cf[(size_t)r * DD + c] = v;
          }
        }
      }
    }
  }
}

// ---------------- launcher ----------------
extern "C" void kernel_launch(void* const* d_in, const int* in_sizes, int n_in,
                              void* d_out, int out_size, void* d_ws, size_t ws_size,
                              hipStream_t stream) {
  const int*   node = (const int*)d_in[0];
  const int*   srcv = (const int*)d_in[1];
  const int*   dstv = (const int*)d_in[2];
  const float* emb  = (const float*)d_in[3];
  const float* W1s  = (const float*)d_in[4];
  const float* W1n  = (const float*)d_in[5];
  const float* b1   = (const float*)d_in[6];
  const float* W2s  = (const float*)d_in[7];
  const float* W2n  = (const float*)d_in[8];
  const float* b2   = (const float*)d_in[9];
  float* out = (float*)d_out;

  char* ws = (char*)d_ws;
  __bf16* xcat = (__bf16*)ws; ws += (size_t)MPAD * KCAT * 2;   // 41.9 MB  [x | hneigh1]
  __bf16* hcat = (__bf16*)ws; ws += (size_t)MPAD * KCAT * 2;   // 41.9 MB  [h1 | hneigh2]
  __bf16* Wt1  = (__bf16*)ws; ws += (size_t)DD * KCAT * 2;     // 4.2 MB
  __bf16* Wt2  = (__bf16*)ws; ws += (size_t)DD * KCAT * 2;     // 4.2 MB
  int* deg    = (int*)ws; ws += 40960;
  int* cursor = (int*)ws; ws += 40960;
  int* off    = (int*)ws; ws += 40960;
  int* eidx   = (int*)ws; ws += (size_t)N_EDGES * 4;

  hipMemsetAsync(deg, 0, 2 * 40960, stream);   // deg + cursor contiguous

  // CSR by dst
  k_hist<<<(N_EDGES + 255) / 256, 256, 0, stream>>>(dstv, deg);
  k_scan<<<1, 1024, 0, stream>>>(deg, off);
  k_fill<<<(N_EDGES + 255) / 256, 256, 0, stream>>>(srcv, dstv, off, cursor, eidx);

  // inputs -> bf16
  k_embed<<<N_NODES, 256, 0, stream>>>(node, emb, xcat);
  k_wconv<<<dim3(64, 32), dim3(32, 8), 0, stream>>>(W1s, W1n, Wt1);
  k_wconv<<<dim3(64, 32), dim3(32, 8), 0, stream>>>(W2s, W2n, Wt2);

  // layer 1
  k_agg<<<AGG_BLOCKS, 256, 0, stream>>>(xcat, off, eidx);
  k_gemm<1><<<NBLK, 256, 0, stream>>>(xcat, Wt1, b1, nullptr, hcat, N_NODES);

  // layer 2
  k_agg<<<AGG_BLOCKS, 256, 0, stream>>>(hcat, off, eidx);
  k_gemm<0><<<NBLK, 256, 0, stream>>>(hcat, Wt2, b2, out, nullptr, N_NODES);
}

// Round 4
// 435.792 us; speedup vs baseline: 1.1902x; 1.1902x over previous
//
#include <hip/hip_runtime.h>
#include <hip/hip_bf16.h>

#define N_NODES 10000
#define N_EDGES 160000
#define DD 1024
#define KCAT 2048
#define MPAD 10240
#define MTILES 79   // ceil(10000/128), covers rows 0..10111
#define NTILES 8
#define NBLK (MTILES * NTILES)   // 632 = 8*79

// agg grid: 8 column-slices (one per XCD via blockIdx%8) x 250 blocks
#define AGG_BLOCKS 2000
#define AGG_WPS 1000   // waves per slice = (AGG_BLOCKS/8)*4

typedef __attribute__((ext_vector_type(8))) __bf16 bf16x8;
typedef __attribute__((ext_vector_type(4))) __bf16 bf16x4;
typedef __attribute__((ext_vector_type(4))) float f32x4;

// ---------------- async global->LDS (16B, linear dest) ----------------
__device__ inline void gload_lds16(const void* g, void* l) {
  __builtin_amdgcn_global_load_lds((const __attribute__((address_space(1))) void*)g,
                                   (__attribute__((address_space(3))) void*)l, 16, 0, 0);
}

// ---------------- CSR build ----------------
__global__ __launch_bounds__(256) void k_hist(const int* __restrict__ dst,
                                              int* __restrict__ deg) {
  int e = blockIdx.x * 256 + threadIdx.x;
  if (e < N_EDGES) atomicAdd(&deg[dst[e]], 1);
}

// coalesced chunked scan: 10 chunks x 1024 contiguous, 2 barriers/chunk
__global__ __launch_bounds__(1024) void k_scan(const int* __restrict__ deg,
                                               int* __restrict__ off) {
  __shared__ int wtot[16];
  __shared__ int wpre[16];
  __shared__ int carry_s;
  int t = threadIdx.x, lane = t & 63, w = t >> 6;
  if (t == 0) carry_s = 0;
  __syncthreads();
  for (int c = 0; c < 10; ++c) {
    int idx = c * 1024 + t;
    int v = (idx < N_NODES) ? deg[idx] : 0;
    int inc = v;
#pragma unroll
    for (int d = 1; d < 64; d <<= 1) {
      int y = __shfl_up(inc, d);
      if (lane >= d) inc += y;
    }
    if (lane == 63) wtot[w] = inc;
    __syncthreads();
    if (t == 0) {
      int acc = carry_s;
      for (int k = 0; k < 16; ++k) { wpre[k] = acc; acc += wtot[k]; }
      carry_s = acc;
    }
    __syncthreads();
    if (idx < N_NODES) off[idx] = wpre[w] + (inc - v);   // exclusive
  }
  if (t == 0) off[N_NODES] = carry_s;
}

__global__ __launch_bounds__(256) void k_fill(const int* __restrict__ src,
                                              const int* __restrict__ dst,
                                              const int* __restrict__ off,
                                              int* __restrict__ cursor,
                                              int* __restrict__ eidx) {
  int e = blockIdx.x * 256 + threadIdx.x;
  if (e < N_EDGES) {
    int d = dst[e];
    int pos = atomicAdd(&cursor[d], 1);
    eidx[off[d] + pos] = src[e];
  }
}

// ---------------- embedding gather -> bf16 (left half of xcat) ----------------
__global__ __launch_bounds__(256) void k_embed(const int* __restrict__ node,
                                               const float* __restrict__ emb,
                                               __bf16* __restrict__ xcat) {
  int i = blockIdx.x;
  int t = threadIdx.x;
  float4 v = ((const float4*)(emb + (size_t)node[i] * DD))[t];
  bf16x4 o;
  o[0] = (__bf16)v.x; o[1] = (__bf16)v.y; o[2] = (__bf16)v.z; o[3] = (__bf16)v.w;
  *(bf16x4*)(xcat + (size_t)i * KCAT + t * 4) = o;
}

// ---------------- weights: both layers in one launch (z = layer) ----------------
__global__ __launch_bounds__(256) void k_wconv(const float* __restrict__ W1s,
                                               const float* __restrict__ W1n,
                                               const float* __restrict__ W2s,
                                               const float* __restrict__ W2n,
                                               __bf16* __restrict__ Wt1,
                                               __bf16* __restrict__ Wt2) {
  const float* Ws = blockIdx.z ? W2s : W1s;
  const float* Wn = blockIdx.z ? W2n : W1n;
  __bf16* Wt = blockIdx.z ? Wt2 : Wt1;
  __shared__ float tile[32][33];
  int k0 = blockIdx.x * 32;
  int c0 = blockIdx.y * 32;
  for (int i = threadIdx.y; i < 32; i += 8) {
    int k = k0 + i, c = c0 + threadIdx.x;
    float v = (k < DD) ? Ws[(size_t)k * DD + c] : Wn[(size_t)(k - DD) * DD + c];
    tile[i][threadIdx.x] = v;
  }
  __syncthreads();
  for (int i = threadIdx.y; i < 32; i += 8) {
    int c = c0 + i, k = k0 + threadIdx.x;
    Wt[(size_t)c * KCAT + k] = (__bf16)tile[threadIdx.x][i];
  }
}

// ---------------- mean aggregation: XCD-pinned slices, 4 edges/load ----------------
// Slice s = blockIdx%8 -> XCD s; slice reads cols [128s,128s+128) of all nodes
// (2.56 MB, L2-resident). Lane (g,l): group g=lane>>4 handles edge eidx[i+g],
// lane reads 16B of that edge's 256B slice-row -> ONE dwordx4 load covers 4
// edges. Unroll x2 => 8 edges in flight/wave. Cross-group shfl_xor reduce.
__global__ __launch_bounds__(256) void k_agg(__bf16* __restrict__ buf,
                                             const int* __restrict__ off,
                                             const int* __restrict__ eidx) {
  const int s    = blockIdx.x & 7;            // column slice / XCD
  const int q    = blockIdx.x >> 3;           // 0..249
  const int lane = threadIdx.x & 63;
  const int w    = threadIdx.x >> 6;
  const int g    = lane >> 4;                 // edge group 0..3
  const int l    = lane & 15;                 // 16 lanes x 16B = 256B slice-row
  const int wid  = q * 4 + w;                 // 0..999
  const size_t colb = (size_t)s * 128 + l * 8;

  for (int n = wid; n < N_NODES; n += AGG_WPS) {
    const int s0 = off[n], e0 = off[n + 1];
    float acc[8];
#pragma unroll
    for (int j = 0; j < 8; ++j) acc[j] = 0.f;
    int i = s0;
    for (; i + 8 <= e0; i += 8) {
      int eA = eidx[i + g];
      int eB = eidx[i + 4 + g];
      bf16x8 vA = *(const bf16x8*)(buf + (size_t)eA * KCAT + colb);
      bf16x8 vB = *(const bf16x8*)(buf + (size_t)eB * KCAT + colb);
#pragma unroll
      for (int j = 0; j < 8; ++j) acc[j] += (float)vA[j] + (float)vB[j];
    }
    if (i + 4 <= e0) {
      int eA = eidx[i + g];
      bf16x8 vA = *(const bf16x8*)(buf + (size_t)eA * KCAT + colb);
#pragma unroll
      for (int j = 0; j < 8; ++j) acc[j] += (float)vA[j];
      i += 4;
    }
    int rem = e0 - i;            // 0..3
    if (g < rem) {
      int eA = eidx[i + g];
      bf16x8 vA = *(const bf16x8*)(buf + (size_t)eA * KCAT + colb);
#pragma unroll
      for (int j = 0; j < 8; ++j) acc[j] += (float)vA[j];
    }
    // combine the 4 groups (lane bits 4,5); all lanes participate
#pragma unroll
    for (int j = 0; j < 8; ++j) {
      acc[j] += __shfl_xor(acc[j], 16);
      acc[j] += __shfl_xor(acc[j], 32);
    }
    if (g == 0) {
      float inv = 1.0f / fmaxf((float)(e0 - s0), 1.0f);
      bf16x8 o;
#pragma unroll
      for (int j = 0; j < 8; ++j) o[j] = (__bf16)(acc[j] * inv);
      *(bf16x8*)(buf + (size_t)n * KCAT + DD + colb) = o;
    }
  }
}

// ---------------- GEMM: C[M,1024] = A[M,2048] @ Wt^T + bias ----------------
// 128x128 tile, BK=64, 4 waves (2x2), T3-minimum 2-phase double-buffered LDS.
// Pre-swizzled global source + XOR-swizzled ds_read, linear gload_lds dest.
// Block decode: bijective XCD-chunked, N-fastest (632 = 8*79).
template <int MODE>
__global__ __launch_bounds__(256, 2) void k_gemm(const __bf16* __restrict__ A,
                                                 const __bf16* __restrict__ Bt,
                                                 const float* __restrict__ bias,
                                                 float* __restrict__ Cf,
                                                 __bf16* __restrict__ Cb,
                                                 int Mreal) {
  __shared__ char smem[65536];
  const int tid  = threadIdx.x;
  const int lane = tid & 63;
  const int w    = tid >> 6;
  const int wr   = w >> 1, wc = w & 1;
  const int b  = blockIdx.x;
  const int l  = (b & 7) * MTILES + (b >> 3);
  const int m0 = (l >> 3) * 128;
  const int n0 = (l & 7) * 128;

  f32x4 acc[4][4];
#pragma unroll
  for (int m = 0; m < 4; ++m)
#pragma unroll
    for (int n = 0; n < 4; ++n) acc[m][n] = f32x4{0.f, 0.f, 0.f, 0.f};

  int sr[4], sk[4];
#pragma unroll
  for (int i = 0; i < 4; ++i) {
    int G = (4 * w + i) * 64 + lane;
    int E = G ^ ((G >> 3) & 7);
    sr[i] = E >> 3;
    sk[i] = (E & 7) * 8;
  }

  auto stage = [&](int buf, int kt) {
    char* As = smem + buf * 32768;
    char* Bs = As + 16384;
#pragma unroll
    for (int i = 0; i < 4; ++i) {
      gload_lds16(A + (size_t)(m0 + sr[i]) * KCAT + (kt + sk[i]), As + (4 * w + i) * 1024);
      gload_lds16(Bt + (size_t)(n0 + sr[i]) * KCAT + (kt + sk[i]), Bs + (4 * w + i) * 1024);
    }
  };

  auto compute = [&](int buf) {
    char* As = smem + buf * 32768;
    char* Bs = As + 16384;
#pragma unroll
    for (int kk = 0; kk < 64; kk += 32) {
      const int koff = kk + ((lane >> 4) * 8);
      bf16x8 af[4], bfr[4];
#pragma unroll
      for (int m = 0; m < 4; ++m) {
        int r = wr * 64 + m * 16 + (lane & 15);
        int byte = ((r * 64 + koff) * 2) ^ ((r & 7) << 4);
        af[m] = *(const bf16x8*)(As + byte);
      }
#pragma unroll
      for (int n = 0; n < 4; ++n) {
        int c = wc * 64 + n * 16 + (lane & 15);
        int byte = ((c * 64 + koff) * 2) ^ ((c & 7) << 4);
        bfr[n] = *(const bf16x8*)(Bs + byte);
      }
#pragma unroll
      for (int m = 0; m < 4; ++m)
#pragma unroll
        for (int n = 0; n < 4; ++n)
          acc[m][n] = __builtin_amdgcn_mfma_f32_16x16x32_bf16(af[m], bfr[n], acc[m][n], 0, 0, 0);
    }
  };

  stage(0, 0);
  __syncthreads();
  int cur = 0;
  for (int kt = 0; kt < KCAT; kt += 64) {
    if (kt + 64 < KCAT) stage(cur ^ 1, kt + 64);
    compute(cur);
    __syncthreads();
    cur ^= 1;
  }

  const int rb = m0 + wr * 64;
  const int cb = n0 + wc * 64;
#pragma unroll
  for (int m = 0; m < 4; ++m) {
#pragma unroll
    for (int n = 0; n < 4; ++n) {
      int c = cb + n * 16 + (lane & 15);
      float bv = bias[c];
#pragma unroll
      for (int j = 0; j < 4; ++j) {
        int r = rb + m * 16 + (lane >> 4) * 4 + j;
        if (r < Mreal) {
          float v = acc[m][n][j] + bv;
          if constexpr (MODE == 1) {
            v = fmaxf(v, 0.f);
            Cb[(size_t)r * KCAT + c] = (__bf16)v;
          } else {
            Cf[(size_t)r * DD + c] = v;
          }
        }
      }
    }
  }
}

// ---------------- launcher ----------------
extern "C" void kernel_launch(void* const* d_in, const int* in_sizes, int n_in,
                              void* d_out, int out_size, void* d_ws, size_t ws_size,
                              hipStream_t stream) {
  const int*   node = (const int*)d_in[0];
  const int*   srcv = (const int*)d_in[1];
  const int*   dstv = (const int*)d_in[2];
  const float* emb  = (const float*)d_in[3];
  const float* W1s  = (const float*)d_in[4];
  const float* W1n  = (const float*)d_in[5];
  const float* b1   = (const float*)d_in[6];
  const float* W2s  = (const float*)d_in[7];
  const float* W2n  = (const float*)d_in[8];
  const float* b2   = (const float*)d_in[9];
  float* out = (float*)d_out;

  char* ws = (char*)d_ws;
  __bf16* xcat = (__bf16*)ws; ws += (size_t)MPAD * KCAT * 2;   // 41.9 MB  [x | hneigh1]
  __bf16* hcat = (__bf16*)ws; ws += (size_t)MPAD * KCAT * 2;   // 41.9 MB  [h1 | hneigh2]
  __bf16* Wt1  = (__bf16*)ws; ws += (size_t)DD * KCAT * 2;     // 4.2 MB
  __bf16* Wt2  = (__bf16*)ws; ws += (size_t)DD * KCAT * 2;     // 4.2 MB
  int* deg    = (int*)ws; ws += 40960;
  int* cursor = (int*)ws; ws += 40960;
  int* off    = (int*)ws; ws += 40960;
  int* eidx   = (int*)ws; ws += (size_t)N_EDGES * 4;

  hipMemsetAsync(deg, 0, 2 * 40960, stream);   // deg + cursor contiguous

  // CSR by dst
  k_hist<<<(N_EDGES + 255) / 256, 256, 0, stream>>>(dstv, deg);
  k_scan<<<1, 1024, 0, stream>>>(deg, off);
  k_fill<<<(N_EDGES + 255) / 256, 256, 0, stream>>>(srcv, dstv, off, cursor, eidx);

  // inputs -> bf16
  k_embed<<<N_NODES, 256, 0, stream>>>(node, emb, xcat);
  k_wconv<<<dim3(64, 32, 2), dim3(32, 8), 0, stream>>>(W1s, W1n, W2s, W2n, Wt1, Wt2);

  // layer 1
  k_agg<<<AGG_BLOCKS, 256, 0, stream>>>(xcat, off, eidx);
  k_gemm<1><<<NBLK, 256, 0, stream>>>(xcat, Wt1, b1, nullptr, hcat, N_NODES);

  // layer 2
  k_agg<<<AGG_BLOCKS, 256, 0, stream>>>(hcat, off, eidx);
  k_gemm<0><<<NBLK, 256, 0, stream>>>(hcat, Wt2, b2, out, nullptr, N_NODES);
}

// Round 6
// 415.357 us; speedup vs baseline: 1.2488x; 1.0492x over previous
//
#include <hip/hip_runtime.h>
#include <hip/hip_bf16.h>

#define N_NODES 10000
#define N_EDGES 160000
#define DD 1024
#define KCAT 2048
#define MPAD 10240
#define MTILES 79   // ceil(10000/128)
#define NTILES 8
#define NBLK (MTILES * NTILES)   // 632 = 8*79
#define NSTEP 64                 // KCAT / 32

// agg grid: 8 column-slices (one per XCD via blockIdx%8) x 250 blocks
#define AGG_BLOCKS 2000
#define AGG_WPS 1000

typedef __attribute__((ext_vector_type(8))) __bf16 bf16x8;
typedef __attribute__((ext_vector_type(4))) __bf16 bf16x4;
typedef __attribute__((ext_vector_type(4))) float f32x4;

__device__ inline void gload_lds16(const void* g, void* l) {
  __builtin_amdgcn_global_load_lds((const __attribute__((address_space(1))) void*)g,
                                   (__attribute__((address_space(3))) void*)l, 16, 0, 0);
}

// ---------------- prep1: hist (blocks 0..624) + embed gather (blocks 625..10624) ----
__global__ __launch_bounds__(256) void k_prep1(const int* __restrict__ dst,
                                               int* __restrict__ deg,
                                               const int* __restrict__ node,
                                               const float* __restrict__ emb,
                                               __bf16* __restrict__ xcat) {
  int b = blockIdx.x;
  if (b < 625) {
    int e = b * 256 + threadIdx.x;
    if (e < N_EDGES) atomicAdd(&deg[dst[e]], 1);
  } else {
    int i = b - 625;          // node 0..9999
    int t = threadIdx.x;
    float4 v = ((const float4*)(emb + (size_t)node[i] * DD))[t];
    bf16x4 o;
    o[0] = (__bf16)v.x; o[1] = (__bf16)v.y; o[2] = (__bf16)v.z; o[3] = (__bf16)v.w;
    *(bf16x4*)(xcat + (size_t)i * KCAT + t * 4) = o;
  }
}

// coalesced chunked scan: 10 chunks x 1024 contiguous, 2 barriers/chunk
__global__ __launch_bounds__(1024) void k_scan(const int* __restrict__ deg,
                                               int* __restrict__ off) {
  __shared__ int wtot[16];
  __shared__ int wpre[16];
  __shared__ int carry_s;
  int t = threadIdx.x, lane = t & 63, w = t >> 6;
  if (t == 0) carry_s = 0;
  __syncthreads();
  for (int c = 0; c < 10; ++c) {
    int idx = c * 1024 + t;
    int v = (idx < N_NODES) ? deg[idx] : 0;
    int inc = v;
#pragma unroll
    for (int d = 1; d < 64; d <<= 1) {
      int y = __shfl_up(inc, d);
      if (lane >= d) inc += y;
    }
    if (lane == 63) wtot[w] = inc;
    __syncthreads();
    if (t == 0) {
      int acc = carry_s;
      for (int k = 0; k < 16; ++k) { wpre[k] = acc; acc += wtot[k]; }
      carry_s = acc;
    }
    __syncthreads();
    if (idx < N_NODES) off[idx] = wpre[w] + (inc - v);
  }
  if (t == 0) off[N_NODES] = carry_s;
}

// ---------------- prep2: fill (blocks 0..624) + wconv (blocks 625..4720) ----------
__global__ __launch_bounds__(256) void k_prep2(const int* __restrict__ src,
                                               const int* __restrict__ dstv,
                                               const int* __restrict__ off,
                                               int* __restrict__ cursor,
                                               int* __restrict__ eidx,
                                               const float* __restrict__ W1s,
                                               const float* __restrict__ W1n,
                                               const float* __restrict__ W2s,
                                               const float* __restrict__ W2n,
                                               __bf16* __restrict__ Wt1,
                                               __bf16* __restrict__ Wt2) {
  int b = blockIdx.x;
  if (b < 625) {
    int e = b * 256 + threadIdx.x;
    if (e < N_EDGES) {
      int d = dstv[e];
      int pos = atomicAdd(&cursor[d], 1);
      eidx[off[d] + pos] = src[e];
    }
    return;
  }
  int id = b - 625;            // 0..4095
  int k0 = (id & 63) * 32;     // 0..2047
  int c0 = ((id >> 6) & 31) * 32;
  int lay = id >> 11;
  const float* Ws = lay ? W2s : W1s;
  const float* Wn = lay ? W2n : W1n;
  __bf16* Wt = lay ? Wt2 : Wt1;
  __shared__ float tile[32][33];
  int tx = threadIdx.x & 31, ty = threadIdx.x >> 5;
  for (int i = ty; i < 32; i += 8) {
    int k = k0 + i, c = c0 + tx;
    float v = (k < DD) ? Ws[(size_t)k * DD + c] : Wn[(size_t)(k - DD) * DD + c];
    tile[i][tx] = v;
  }
  __syncthreads();
  for (int i = ty; i < 32; i += 8) {
    int c = c0 + i, k = k0 + tx;
    Wt[(size_t)c * KCAT + k] = (__bf16)tile[tx][i];
  }
}

// ---------------- mean aggregation: XCD-pinned slices, 4 edges/load (R4, proven) ---
__global__ __launch_bounds__(256) void k_agg(__bf16* __restrict__ buf,
                                             const int* __restrict__ off,
                                             const int* __restrict__ eidx) {
  const int s    = blockIdx.x & 7;
  const int q    = blockIdx.x >> 3;
  const int lane = threadIdx.x & 63;
  const int w    = threadIdx.x >> 6;
  const int g    = lane >> 4;
  const int l    = lane & 15;
  const int wid  = q * 4 + w;
  const size_t colb = (size_t)s * 128 + l * 8;

  for (int n = wid; n < N_NODES; n += AGG_WPS) {
    const int s0 = off[n], e0 = off[n + 1];
    float acc[8];
#pragma unroll
    for (int j = 0; j < 8; ++j) acc[j] = 0.f;
    int i = s0;
    for (; i + 8 <= e0; i += 8) {
      int eA = eidx[i + g];
      int eB = eidx[i + 4 + g];
      bf16x8 vA = *(const bf16x8*)(buf + (size_t)eA * KCAT + colb);
      bf16x8 vB = *(const bf16x8*)(buf + (size_t)eB * KCAT + colb);
#pragma unroll
      for (int j = 0; j < 8; ++j) acc[j] += (float)vA[j] + (float)vB[j];
    }
    if (i + 4 <= e0) {
      int eA = eidx[i + g];
      bf16x8 vA = *(const bf16x8*)(buf + (size_t)eA * KCAT + colb);
#pragma unroll
      for (int j = 0; j < 8; ++j) acc[j] += (float)vA[j];
      i += 4;
    }
    int rem = e0 - i;
    if (g < rem) {
      int eA = eidx[i + g];
      bf16x8 vA = *(const bf16x8*)(buf + (size_t)eA * KCAT + colb);
#pragma unroll
      for (int j = 0; j < 8; ++j) acc[j] += (float)vA[j];
    }
#pragma unroll
    for (int j = 0; j < 8; ++j) {
      acc[j] += __shfl_xor(acc[j], 16);
      acc[j] += __shfl_xor(acc[j], 32);
    }
    if (g == 0) {
      float inv = 1.0f / fmaxf((float)(e0 - s0), 1.0f);
      bf16x8 o;
#pragma unroll
      for (int j = 0; j < 8; ++j) o[j] = (__bf16)(acc[j] * inv);
      *(bf16x8*)(buf + (size_t)n * KCAT + DD + colb) = o;
    }
  }
}

// ---------------- GEMM: 128x128 tile, BK=32, triple-buffer, distance-2 prefetch ----
// T3+T4: stage buf[(t+2)%3] each step; s_waitcnt vmcnt(8) certifies ONLY the
// 2-steps-old loads of buf[t%3] (issued 2 compute phases ago -> latency hidden);
// raw s_barrier (no vmcnt(0) drain); sched_barrier(0) fences (rule #18).
// Buffer staged at t was last read at t-1 (certified dead by t-1's end barrier).
// LDS 48KB -> 3 blocks/CU. Swizzle: 64B rows, chunk ^= (row>>1)&3 (16B units),
// pre-swizzled global source + swizzled ds_read, linear gload_lds dest (rule #21).
template <int MODE>
__global__ __launch_bounds__(256, 3) void k_gemm(const __bf16* __restrict__ A,
                                                 const __bf16* __restrict__ Bt,
                                                 const float* __restrict__ bias,
                                                 float* __restrict__ Cf,
                                                 __bf16* __restrict__ Cb,
                                                 int Mreal) {
  __shared__ char smem[49152];   // 3 x (A 8KB | B 8KB)
  const int tid  = threadIdx.x;
  const int lane = tid & 63;
  const int w    = tid >> 6;
  const int wr   = w >> 1, wc = w & 1;
  const int b  = blockIdx.x;
  const int l  = (b & 7) * MTILES + (b >> 3);
  const int m0 = (l >> 3) * 128;
  const int n0 = (l & 7) * 128;

  f32x4 acc[4][4];
#pragma unroll
  for (int m = 0; m < 4; ++m)
#pragma unroll
    for (int n = 0; n < 4; ++n) acc[m][n] = f32x4{0.f, 0.f, 0.f, 0.f};

  // staging coords: granule G = i*256 + tid (16B units); row = G>>2;
  // src chunk = (G&3) ^ ((row>>1)&3)  (inverse of the ds_read swizzle)
  int srow[2], sko[2];
#pragma unroll
  for (int i = 0; i < 2; ++i) {
    int G = i * 256 + tid;
    srow[i] = G >> 2;
    sko[i] = ((G & 3) ^ ((srow[i] >> 1) & 3)) * 8;   // bf16 offset within BK=32
  }

  auto stage = [&](int buf, int kt) {
    char* Ab = smem + buf * 16384;
    char* Bb = Ab + 8192;
#pragma unroll
    for (int i = 0; i < 2; ++i) {
      gload_lds16(A + (size_t)(m0 + srow[i]) * KCAT + (kt + sko[i]), Ab + i * 4096 + w * 1024);
      gload_lds16(Bt + (size_t)(n0 + srow[i]) * KCAT + (kt + sko[i]), Bb + i * 4096 + w * 1024);
    }
  };

  auto compute = [&](int buf) {
    char* Ab = smem + buf * 16384;
    char* Bb = Ab + 8192;
    const int c = lane >> 4;                 // 16B chunk within 64B row
    bf16x8 af[4], bfr[4];
#pragma unroll
    for (int m = 0; m < 4; ++m) {
      int r = wr * 64 + m * 16 + (lane & 15);
      af[m] = *(const bf16x8*)(Ab + r * 64 + ((c ^ ((r >> 1) & 3)) << 4));
    }
#pragma unroll
    for (int n = 0; n < 4; ++n) {
      int r = wc * 64 + n * 16 + (lane & 15);
      bfr[n] = *(const bf16x8*)(Bb + r * 64 + ((c ^ ((r >> 1) & 3)) << 4));
    }
#pragma unroll
    for (int m = 0; m < 4; ++m)
#pragma unroll
      for (int n = 0; n < 4; ++n)
        acc[m][n] = __builtin_amdgcn_mfma_f32_16x16x32_bf16(af[m], bfr[n], acc[m][n], 0, 0, 0);
  };

  stage(0, 0);
  stage(1, 32);
  int cur = 0, nxt = 2;
  for (int t = 0; t < NSTEP; ++t) {
    if (t + 2 < NSTEP) {
      stage(nxt, (t + 2) * 32);
      asm volatile("s_waitcnt vmcnt(8)" ::: "memory");
    } else if (t + 1 < NSTEP) {
      asm volatile("s_waitcnt vmcnt(4)" ::: "memory");
    } else {
      asm volatile("s_waitcnt vmcnt(0)" ::: "memory");
    }
    __builtin_amdgcn_sched_barrier(0);
    __builtin_amdgcn_s_barrier();          // all waves certified buf[cur]
    __builtin_amdgcn_sched_barrier(0);
    compute(cur);
    __builtin_amdgcn_sched_barrier(0);
    __builtin_amdgcn_s_barrier();          // all waves done reading buf[cur]
    __builtin_amdgcn_sched_barrier(0);
    cur = (cur == 2) ? 0 : cur + 1;
    nxt = (nxt == 2) ? 0 : nxt + 1;
  }

  // epilogue: C/D layout col=lane&15, row=(lane>>4)*4+j (m89-verified)
  const int rb = m0 + wr * 64;
  const int cb = n0 + wc * 64;
#pragma unroll
  for (int m = 0; m < 4; ++m) {
#pragma unroll
    for (int n = 0; n < 4; ++n) {
      int cc = cb + n * 16 + (lane & 15);
      float bv = bias[cc];
#pragma unroll
      for (int j = 0; j < 4; ++j) {
        int r = rb + m * 16 + (lane >> 4) * 4 + j;
        if (r < Mreal) {
          float v = acc[m][n][j] + bv;
          if constexpr (MODE == 1) {
            v = fmaxf(v, 0.f);
            Cb[(size_t)r * KCAT + cc] = (__bf16)v;
          } else {
            Cf[(size_t)r * DD + cc] = v;
          }
        }
      }
    }
  }
}

// ---------------- launcher ----------------
extern "C" void kernel_launch(void* const* d_in, const int* in_sizes, int n_in,
                              void* d_out, int out_size, void* d_ws, size_t ws_size,
                              hipStream_t stream) {
  const int*   node = (const int*)d_in[0];
  const int*   srcv = (const int*)d_in[1];
  const int*   dstv = (const int*)d_in[2];
  const float* emb  = (const float*)d_in[3];
  const float* W1s  = (const float*)d_in[4];
  const float* W1n  = (const float*)d_in[5];
  const float* b1   = (const float*)d_in[6];
  const float* W2s  = (const float*)d_in[7];
  const float* W2n  = (const float*)d_in[8];
  const float* b2   = (const float*)d_in[9];
  float* out = (float*)d_out;

  char* ws = (char*)d_ws;
  __bf16* xcat = (__bf16*)ws; ws += (size_t)MPAD * KCAT * 2;   // [x | hneigh1]
  __bf16* hcat = (__bf16*)ws; ws += (size_t)MPAD * KCAT * 2;   // [h1 | hneigh2]
  __bf16* Wt1  = (__bf16*)ws; ws += (size_t)DD * KCAT * 2;
  __bf16* Wt2  = (__bf16*)ws; ws += (size_t)DD * KCAT * 2;
  int* deg    = (int*)ws; ws += 40960;
  int* cursor = (int*)ws; ws += 40960;
  int* off    = (int*)ws; ws += 40960;
  int* eidx   = (int*)ws; ws += (size_t)N_EDGES * 4;

  hipMemsetAsync(deg, 0, 2 * 40960, stream);   // deg + cursor contiguous

  k_prep1<<<625 + N_NODES, 256, 0, stream>>>(dstv, deg, node, emb, xcat);
  k_scan<<<1, 1024, 0, stream>>>(deg, off);
  k_prep2<<<625 + 4096, 256, 0, stream>>>(srcv, dstv, off, cursor, eidx,
                                          W1s, W1n, W2s, W2n, Wt1, Wt2);

  // layer 1
  k_agg<<<AGG_BLOCKS, 256, 0, stream>>>(xcat, off, eidx);
  k_gemm<1><<<NBLK, 256, 0, stream>>>(xcat, Wt1, b1, nullptr, hcat, N_NODES);

  // layer 2
  k_agg<<<AGG_BLOCKS, 256, 0, stream>>>(hcat, off, eidx);
  k_gemm<0><<<NBLK, 256, 0, stream>>>(hcat, Wt2, b2, out, nullptr, N_NODES);
}